// Round 8
// baseline (1243.177 us; speedup 1.0000x reference)
//
#include <hip/hip_runtime.h>

typedef __attribute__((ext_vector_type(8))) __bf16 bf16x8;
typedef __attribute__((ext_vector_type(4))) float f32x4;

#define IMG 112
#define SHF 3
#define OS 8704  // o_s base in lds (ushorts); x_s = [0, 8704) = [64][136]

__device__ __forceinline__ ushort f2bf(float f) {
  return __builtin_bit_cast(unsigned short, static_cast<__bf16>(f));
}
__device__ __forceinline__ uint pk2(float lo, float hi) {
  return (uint)f2bf(lo) | ((uint)f2bf(hi) << 16);
}
__device__ __forceinline__ int d7(int n) { return (n * 9363) >> 16; }  // n/7 for n<=63

// In-register repack (verified in R4/R5): two D-frags (rows 0-15 in d0, 16-31 in d1,
// this lane's column = lr) -> one A/B-operand fragment where lane (lr,kg) holds
// k = kg*8..kg*8+7 as 8 bf16. aA=((kg&1)*32+lr)*4, aB=aA+64, lo=(kg<2).
__device__ __forceinline__ bf16x8 repackB(f32x4 d0, f32x4 d1, int aA, int aB, bool lo) {
  uint pk00 = pk2(d0[0], d0[1]);
  uint pk01 = pk2(d0[2], d0[3]);
  uint pk10 = pk2(d1[0], d1[1]);
  uint pk11 = pk2(d1[2], d1[3]);
  uint b00 = (uint)__builtin_amdgcn_ds_bpermute(aA, (int)pk00);
  uint b10 = (uint)__builtin_amdgcn_ds_bpermute(aA, (int)pk10);
  uint b01 = (uint)__builtin_amdgcn_ds_bpermute(aA, (int)pk01);
  uint b11 = (uint)__builtin_amdgcn_ds_bpermute(aA, (int)pk11);
  uint b02 = (uint)__builtin_amdgcn_ds_bpermute(aB, (int)pk00);
  uint b12 = (uint)__builtin_amdgcn_ds_bpermute(aB, (int)pk10);
  uint b03 = (uint)__builtin_amdgcn_ds_bpermute(aB, (int)pk01);
  uint b13 = (uint)__builtin_amdgcn_ds_bpermute(aB, (int)pk11);
  union { uint4 u; bf16x8 v; } r;
  r.u = uint4{ lo ? b00 : b10, lo ? b01 : b11, lo ? b02 : b12, lo ? b03 : b13 };
  return r.v;
}

// ---------------- prep: bf16 weights (+q scale fold), biases, rpb+mask table ----------------
__global__ void prep_kernel(const float* __restrict__ Wq, const float* __restrict__ Wk,
                            const float* __restrict__ Wv, const float* __restrict__ Wp,
                            const float* __restrict__ bq, const float* __restrict__ bk,
                            const float* __restrict__ bv, const float* __restrict__ bp,
                            const float* __restrict__ tbl,
                            ushort* __restrict__ wW, float* __restrict__ wB,
                            float* __restrict__ wRM) {
  int t = blockIdx.x * 256 + threadIdx.x;
  const float SC = 0.17677669529663687f;  // 32^-0.5
  if (t < 65536) {
    int m = t >> 14, e = t & 16383;
    const float* W = (m == 0) ? Wq : (m == 1) ? Wk : (m == 2) ? Wv : Wp;
    float v = W[e];
    if (m == 0) v *= SC;
    wW[t] = f2bf(v);
  } else if (t < 66048) {
    int t2 = t - 65536;
    int m = t2 >> 7, e = t2 & 127;
    const float* B = (m == 0) ? bq : (m == 1) ? bk : (m == 2) ? bv : bp;
    float v = B[e];
    if (m == 0) v *= SC;
    wB[t2] = v;
  } else if (t < 131584) {
    int t3 = t - 66048;  // [0, 65536)
    int cls = t3 >> 14;
    int r = t3 & 16383;
    int h = r >> 12;
    int rr = r & 4095;
    int qt = rr >> 6, kt = rr & 63;
    float v;
    if (qt >= 49) v = 0.0f;
    else if (kt >= 49) v = -1e30f;
    else {
      int rq = qt / 7, cq = qt % 7, rk = kt / 7, ck = kt % 7;
      v = tbl[((rq - rk + 6) * 13 + (cq - ck + 6)) * 4 + h];
      int eH = (cls >> 1) & 1, eW = cls & 1;
      int ridq = (eH ? (rq < 4 ? 3 : 6) : 0) + (eW ? (cq < 4 ? 1 : 2) : 0);
      int ridk = (eH ? (rk < 4 ? 3 : 6) : 0) + (eW ? (ck < 4 ? 1 : 2) : 0);
      if (ridq != ridk) v -= 100.0f;
    }
    wRM[t3] = v;
  }
}

// Wave = (head h = wv&3, q-half qh = wv>>2). Whole attention in registers; the only
// LDS uses are x_s staging (read-shared) and o_s (head outputs for the final proj).
__global__ __launch_bounds__(512, 4) void swin_kernel(
    const float* __restrict__ X, const ushort* __restrict__ wW,
    const float* __restrict__ wB, const float* __restrict__ wRM,
    float* __restrict__ out) {
  __shared__ ushort lds[15368];
  const int tid = threadIdx.x;
  const int wv = tid >> 6;  // 0..7
  const int lane = tid & 63;
  const int lr = lane & 15;
  const int kg = lane >> 4;

  const int blk = blockIdx.x;
  const int b = blk >> 8;
  const int wid = blk & 255;
  const int wi = wid >> 4, wj = wid & 15;
  const size_t gBase = (size_t)b * (IMG * IMG * 128);

  const int h = wv & 3, qh = wv >> 2;
  const int aA = ((kg & 1) * 32 + lr) * 4;
  const int aB = aA + 64;
  const bool lo = (kg < 2);

  // ---------------- Phase A: gather rolled window -> x_s (rows 49-63 zeroed) ----------------
#pragma unroll 1
  for (int idx = tid; idx < 64 * 32; idx += 512) {
    int row = idx >> 5, q4 = idx & 31;
    ushort4 h4 = {0, 0, 0, 0};
    if (row < 49) {
      int r = d7(row), c = row - r * 7;
      int gh = wi * 7 + r + SHF; if (gh >= IMG) gh -= IMG;
      int gw = wj * 7 + c + SHF; if (gw >= IMG) gw -= IMG;
      float4 v = reinterpret_cast<const float4*>(X + gBase + ((size_t)gh * IMG + gw) * 128)[q4];
      h4 = ushort4{ f2bf(v.x), f2bf(v.y), f2bf(v.z), f2bf(v.w) };
    }
    *reinterpret_cast<ushort4*>(&lds[row * 136 + q4 * 4]) = h4;
  }
  __syncthreads();

  // ---------------- Pass 1: K (all 64 kt) + Q (this wave's 32 qt), head h ----------------
  f32x4 accK[2][4] = {};  // [ct ch-tile][tt kt-tile]  D[ch][tok]
  f32x4 accQ[2][2] = {};  // [ct][bt qt-tile]
#pragma unroll
  for (int kk = 0; kk < 4; ++kk) {
    bf16x8 xv[4];
#pragma unroll
    for (int tt = 0; tt < 4; ++tt)
      xv[tt] = *reinterpret_cast<const bf16x8*>(&lds[(tt * 16 + lr) * 136 + kk * 32 + kg * 8]);
    bf16x8 wk[2], wq[2];
#pragma unroll
    for (int ct = 0; ct < 2; ++ct) {
      wk[ct] = *reinterpret_cast<const bf16x8*>(&wW[16384 + (h * 32 + ct * 16 + lr) * 128 + kk * 32 + kg * 8]);
      wq[ct] = *reinterpret_cast<const bf16x8*>(&wW[(h * 32 + ct * 16 + lr) * 128 + kk * 32 + kg * 8]);
    }
#pragma unroll
    for (int ct = 0; ct < 2; ++ct) {
#pragma unroll
      for (int tt = 0; tt < 4; ++tt)
        accK[ct][tt] = __builtin_amdgcn_mfma_f32_16x16x32_bf16(wk[ct], xv[tt], accK[ct][tt], 0, 0, 0);
#pragma unroll
      for (int bt = 0; bt < 2; ++bt)
        accQ[ct][bt] = __builtin_amdgcn_mfma_f32_16x16x32_bf16(wq[ct], xv[2 * qh + bt], accQ[ct][bt], 0, 0, 0);
    }
  }
  // biases (along ch = regs) then repack to operand frags
  bf16x8 kf[4], qf[2];
  {
    float4 bkv[2], bqv[2];
#pragma unroll
    for (int ct = 0; ct < 2; ++ct) {
      bkv[ct] = *reinterpret_cast<const float4*>(&wB[128 + h * 32 + ct * 16 + kg * 4]);
      bqv[ct] = *reinterpret_cast<const float4*>(&wB[h * 32 + ct * 16 + kg * 4]);
    }
#pragma unroll
    for (int ct = 0; ct < 2; ++ct)
#pragma unroll
      for (int i = 0; i < 4; ++i) {
#pragma unroll
        for (int tt = 0; tt < 4; ++tt) accK[ct][tt][i] += bkv[ct][i];
#pragma unroll
        for (int bt = 0; bt < 2; ++bt) accQ[ct][bt][i] += bqv[ct][i];
      }
#pragma unroll
    for (int tt = 0; tt < 4; ++tt) kf[tt] = repackB(accK[0][tt], accK[1][tt], aA, aB, lo);
#pragma unroll
    for (int bt = 0; bt < 2; ++bt) qf[bt] = repackB(accQ[0][bt], accQ[1][bt], aA, aB, lo);
  }

  // ---------------- Pass 2: V (all 64 kt), head h ----------------
  bf16x8 vf[2][2];  // [ct d-tile][kkc kt-chunk]
  {
    f32x4 accV[4][2] = {};  // [tt kt-tile][ct]  D[tok][ch]
#pragma unroll
    for (int kk = 0; kk < 4; ++kk) {
      bf16x8 xv[4];
#pragma unroll
      for (int tt = 0; tt < 4; ++tt)
        xv[tt] = *reinterpret_cast<const bf16x8*>(&lds[(tt * 16 + lr) * 136 + kk * 32 + kg * 8]);
      bf16x8 wvv[2];
#pragma unroll
      for (int ct = 0; ct < 2; ++ct)
        wvv[ct] = *reinterpret_cast<const bf16x8*>(&wW[32768 + (h * 32 + ct * 16 + lr) * 128 + kk * 32 + kg * 8]);
#pragma unroll
      for (int tt = 0; tt < 4; ++tt)
#pragma unroll
        for (int ct = 0; ct < 2; ++ct)
          accV[tt][ct] = __builtin_amdgcn_mfma_f32_16x16x32_bf16(xv[tt], wvv[ct], accV[tt][ct], 0, 0, 0);
    }
    // bias along ch = lane (col)
    float bvs[2];
#pragma unroll
    for (int ct = 0; ct < 2; ++ct) bvs[ct] = wB[256 + h * 32 + ct * 16 + lr];
#pragma unroll
    for (int tt = 0; tt < 4; ++tt)
#pragma unroll
      for (int ct = 0; ct < 2; ++ct)
#pragma unroll
        for (int i = 0; i < 4; ++i) accV[tt][ct][i] += bvs[ct];
#pragma unroll
    for (int ct = 0; ct < 2; ++ct)
#pragma unroll
      for (int kkc = 0; kkc < 2; ++kkc)
        vf[ct][kkc] = repackB(accV[2 * kkc][ct], accV[2 * kkc + 1][ct], aA, aB, lo);
  }

  // ---------------- S^T = K Q^T (all in regs) ----------------
  f32x4 s[4][2] = {};  // [at kt-tile][bt qt-tile]; lane lr = qt, regs = kt
#pragma unroll
  for (int at = 0; at < 4; ++at)
#pragma unroll
    for (int bt = 0; bt < 2; ++bt)
      s[at][bt] = __builtin_amdgcn_mfma_f32_16x16x32_bf16(kf[at], qf[bt], s[at][bt], 0, 0, 0);

  // ---------------- rpb + mask + exp (no max-subtract; clamp) ----------------
  const int cls = ((wi == 15) ? 2 : 0) + ((wj == 15) ? 1 : 0);
  float sum[2] = {0.0f, 0.0f};
#pragma unroll
  for (int bt = 0; bt < 2; ++bt) {
    int qt = (2 * qh + bt) * 16 + lr;
    const float* rp = wRM + (((size_t)cls * 4 + h) * 64 + qt) * 64 + kg * 4;
#pragma unroll
    for (int at = 0; at < 4; ++at) {
      float4 r4 = *reinterpret_cast<const float4*>(rp + at * 16);
#pragma unroll
      for (int i = 0; i < 4; ++i) {
        float e = __expf(fminf(s[at][bt][i] + r4[i], 60.0f));
        s[at][bt][i] = e; sum[bt] += e;
      }
    }
  }

  // ---------------- P -> B-frags (in regs), O = V^T P^T ----------------
  bf16x8 pf[2][2];  // [kkc][bt]
#pragma unroll
  for (int kkc = 0; kkc < 2; ++kkc)
#pragma unroll
    for (int bt = 0; bt < 2; ++bt)
      pf[kkc][bt] = repackB(s[2 * kkc][bt], s[2 * kkc + 1][bt], aA, aB, lo);

  f32x4 o[2][2] = {};  // [ct d-tile][bt]; lane lr = qt, regs = d
#pragma unroll
  for (int ct = 0; ct < 2; ++ct)
#pragma unroll
    for (int bt = 0; bt < 2; ++bt) {
      o[ct][bt] = __builtin_amdgcn_mfma_f32_16x16x32_bf16(vf[ct][0], pf[0][bt], o[ct][bt], 0, 0, 0);
      o[ct][bt] = __builtin_amdgcn_mfma_f32_16x16x32_bf16(vf[ct][1], pf[1][bt], o[ct][bt], 0, 0, 0);
    }

  // ---------------- normalize + write o_s[tok][ch] ----------------
#pragma unroll
  for (int bt = 0; bt < 2; ++bt) {
    float sm = sum[bt];
    sm += __shfl_xor(sm, 16);
    sm += __shfl_xor(sm, 32);
    float inv = 1.0f / sm;
    int qt = (2 * qh + bt) * 16 + lr;
    if (qt < 49) {
#pragma unroll
      for (int ct = 0; ct < 2; ++ct) {
        ushort4 h4 = { f2bf(o[ct][bt][0] * inv), f2bf(o[ct][bt][1] * inv),
                       f2bf(o[ct][bt][2] * inv), f2bf(o[ct][bt][3] * inv) };
        *reinterpret_cast<ushort4*>(&lds[OS + qt * 136 + h * 32 + ct * 16 + kg * 4]) = h4;
      }
    }
  }
  __syncthreads();

  // ---------------- Phase E: output projection (swapped) + float4 scatter ----------------
  {
    const int c0 = (wv & 3) * 32, t0 = (wv >> 2) * 32;
    const ushort* W = wW + 3 * 16384;
    f32x4 acc[2][2] = {};
#pragma unroll
    for (int kk = 0; kk < 4; ++kk) {
      bf16x8 aw[2], bo[2];
#pragma unroll
      for (int mt = 0; mt < 2; ++mt)
        aw[mt] = *reinterpret_cast<const bf16x8*>(&W[(c0 + mt * 16 + lr) * 128 + kk * 32 + kg * 8]);
#pragma unroll
      for (int nt = 0; nt < 2; ++nt) {
        int tok = t0 + nt * 16 + lr; if (tok > 48) tok = 48;
        bo[nt] = *reinterpret_cast<const bf16x8*>(&lds[OS + tok * 136 + kk * 32 + kg * 8]);
      }
#pragma unroll
      for (int mt = 0; mt < 2; ++mt)
#pragma unroll
        for (int nt = 0; nt < 2; ++nt)
          acc[mt][nt] = __builtin_amdgcn_mfma_f32_16x16x32_bf16(aw[mt], bo[nt], acc[mt][nt], 0, 0, 0);
    }
#pragma unroll
    for (int mt = 0; mt < 2; ++mt) {
      float4 b4 = *reinterpret_cast<const float4*>(&wB[384 + c0 + mt * 16 + kg * 4]);
#pragma unroll
      for (int nt = 0; nt < 2; ++nt) {
        int tok = t0 + nt * 16 + lr;
        if (tok < 49) {
          int r = d7(tok), c = tok - r * 7;
          int gh = wi * 7 + r + SHF; if (gh >= IMG) gh -= IMG;
          int gw = wj * 7 + c + SHF; if (gw >= IMG) gw -= IMG;
          float4 o4 = { acc[mt][nt][0] + b4.x, acc[mt][nt][1] + b4.y,
                        acc[mt][nt][2] + b4.z, acc[mt][nt][3] + b4.w };
          *reinterpret_cast<float4*>(out + gBase + ((size_t)gh * IMG + gw) * 128 + c0 + mt * 16 + kg * 4) = o4;
        }
      }
    }
  }
}

extern "C" void kernel_launch(void* const* d_in, const int* in_sizes, int n_in,
                              void* d_out, int out_size, void* d_ws, size_t ws_size,
                              hipStream_t stream) {
  const float* X = (const float*)d_in[0];
  const float* Wq = (const float*)d_in[3];
  const float* Wk = (const float*)d_in[4];
  const float* Wv = (const float*)d_in[5];
  const float* Wp = (const float*)d_in[6];
  const float* bq = (const float*)d_in[7];
  const float* bk = (const float*)d_in[8];
  const float* bv = (const float*)d_in[9];
  const float* bp = (const float*)d_in[10];
  const float* tbl = (const float*)d_in[11];

  ushort* wW = (ushort*)d_ws;                             // 4 x [128][128] bf16 = 131072 B
  float* wB = (float*)((char*)d_ws + 131072);             // 4 x [128] f32   = 2048 B
  float* wRM = (float*)((char*)d_ws + 131072 + 2048);     // [4][4][64][64] f32 = 262144 B

  prep_kernel<<<dim3(514), dim3(256), 0, stream>>>(Wq, Wk, Wv, Wp, bq, bk, bv, bp, tbl, wW, wB, wRM);
  swin_kernel<<<dim3(8192), dim3(512), 0, stream>>>(X, wW, wB, wRM, (float*)d_out);
}

// Round 9
// 412.484 us; speedup vs baseline: 3.0139x; 3.0139x over previous
//
#include <hip/hip_runtime.h>

typedef __attribute__((ext_vector_type(8))) __bf16 bf16x8;
typedef __attribute__((ext_vector_type(4))) float f32x4;

#define IMG 112
#define SHF 3

__device__ __forceinline__ ushort f2bf(float f) {
  return __builtin_bit_cast(unsigned short, static_cast<__bf16>(f));
}
__device__ __forceinline__ int d7(int n) { return (n * 9363) >> 16; }  // n/7 for n<=63

// ---------------- prep: bf16 weights (+q scale fold), biases, rpb+mask table ----------------
// wRM[cls][h][64 qt][64 kt]: rpb + (-100 shift mask) + (-1e30 for kt>=49 pad); 0 for qt>=49.
__global__ void prep_kernel(const float* __restrict__ Wq, const float* __restrict__ Wk,
                            const float* __restrict__ Wv, const float* __restrict__ Wp,
                            const float* __restrict__ bq, const float* __restrict__ bk,
                            const float* __restrict__ bv, const float* __restrict__ bp,
                            const float* __restrict__ tbl,
                            ushort* __restrict__ wW, float* __restrict__ wB,
                            float* __restrict__ wRM) {
  int t = blockIdx.x * 256 + threadIdx.x;
  const float SC = 0.17677669529663687f;  // 32^-0.5
  if (t < 65536) {
    int m = t >> 14, e = t & 16383;
    const float* W = (m == 0) ? Wq : (m == 1) ? Wk : (m == 2) ? Wv : Wp;
    float v = W[e];
    if (m == 0) v *= SC;
    wW[t] = f2bf(v);
  } else if (t < 66048) {
    int t2 = t - 65536;
    int m = t2 >> 7, e = t2 & 127;
    const float* B = (m == 0) ? bq : (m == 1) ? bk : (m == 2) ? bv : bp;
    float v = B[e];
    if (m == 0) v *= SC;
    wB[t2] = v;
  } else if (t < 131584) {
    int t3 = t - 66048;  // [0, 65536)
    int cls = t3 >> 14;
    int r = t3 & 16383;
    int h = r >> 12;
    int rr = r & 4095;
    int qt = rr >> 6, kt = rr & 63;
    float v;
    if (qt >= 49) v = 0.0f;
    else if (kt >= 49) v = -1e30f;
    else {
      int rq = qt / 7, cq = qt % 7, rk = kt / 7, ck = kt % 7;
      v = tbl[((rq - rk + 6) * 13 + (cq - ck + 6)) * 4 + h];
      int eH = (cls >> 1) & 1, eW = cls & 1;
      int ridq = (eH ? (rq < 4 ? 3 : 6) : 0) + (eW ? (cq < 4 ? 1 : 2) : 0);
      int ridk = (eH ? (rk < 4 ? 3 : 6) : 0) + (eW ? (ck < 4 ? 1 : 2) : 0);
      if (ridq != ridk) v -= 100.0f;
    }
    wRM[t3] = v;
  }
}

// Per-window LDS layout (ushort units, window base = w*31760):
//  +0      : x_s[49][136] (A/B)  |  p_s[2][64][72] (attn)  |  o_s[49][136] (proj in)
//  +9216   : q_s[49][136]
//  +15880  : k_s[49][136]
//  +22544  : vT[128][72]
// Two windows per block: 63520 ushorts = 127040 B -> 1 block/CU, 2 waves/SIMD.
#define QS 9216
#define KS 15880
#define VT 22544

__global__ __launch_bounds__(512, 2) void swin_kernel(
    const float* __restrict__ X, const ushort* __restrict__ wW,
    const float* __restrict__ wB, const float* __restrict__ wRM,
    float* __restrict__ out) {
  __shared__ ushort lds[63520];
  const int tid = threadIdx.x;
  const int wv = tid >> 6;  // 0..7
  const int lane = tid & 63;
  const int lr = lane & 15;
  const int kg = lane >> 4;

  const int blk = blockIdx.x;   // 0..4095
  const int b = blk >> 7;
  const int pair = blk & 127;
  const size_t gBase = (size_t)b * (IMG * IMG * 128);

  int wiA[2], wjA[2], clsA[2];
#pragma unroll
  for (int w = 0; w < 2; ++w) {
    int wid = pair * 2 + w;
    wiA[w] = wid >> 4; wjA[w] = wid & 15;
    clsA[w] = ((wiA[w] == 15) ? 2 : 0) + ((wjA[w] == 15) ? 1 : 0);
  }

  const int wc = wv & 3, wt = wv >> 2;
  const int c0 = wc * 32, t0 = wt * 32;
  const int hloc = wv >> 2, mq = wv & 3;
  const int qt = mq * 16 + lr;
  const int qtc = qt > 48 ? 48 : qt;

  // ---------------- Phase A x2: gather rolled windows, f32 -> bf16 ----------------
#pragma unroll
  for (int w = 0; w < 2; ++w) {
    ushort* L = lds + w * 31760;
    const int wi = wiA[w], wj = wjA[w];
    for (int idx = tid; idx < 49 * 32; idx += 512) {
      int row = idx >> 5, q4 = idx & 31;
      int r = d7(row), c = row - r * 7;
      int gh = wi * 7 + r + SHF; if (gh >= IMG) gh -= IMG;
      int gw = wj * 7 + c + SHF; if (gw >= IMG) gw -= IMG;
      float4 v = reinterpret_cast<const float4*>(X + gBase + ((size_t)gh * IMG + gw) * 128)[q4];
      ushort4 h4 = { f2bf(v.x), f2bf(v.y), f2bf(v.z), f2bf(v.w) };
      *reinterpret_cast<ushort4*>(&L[row * 136 + q4 * 4]) = h4;
    }
  }
  __syncthreads();

  // ---------------- Phase B x2: QKV projections ----------------
#pragma unroll
  for (int w = 0; w < 2; ++w) {
    ushort* L = lds + w * 31760;
#pragma unroll
    for (int pj = 0; pj < 2; ++pj) {  // q, k: D[co][tok]
      const ushort* W = wW + pj * 16384;
      f32x4 acc[2][2] = {};
#pragma unroll
      for (int kk = 0; kk < 4; ++kk) {
        bf16x8 aw[2], bx[2];
#pragma unroll
        for (int mt = 0; mt < 2; ++mt)
          aw[mt] = *reinterpret_cast<const bf16x8*>(&W[(c0 + mt * 16 + lr) * 128 + kk * 32 + kg * 8]);
#pragma unroll
        for (int nt = 0; nt < 2; ++nt) {
          int tok = t0 + nt * 16 + lr; if (tok > 48) tok = 48;
          bx[nt] = *reinterpret_cast<const bf16x8*>(&L[tok * 136 + kk * 32 + kg * 8]);
        }
#pragma unroll
        for (int mt = 0; mt < 2; ++mt)
#pragma unroll
          for (int nt = 0; nt < 2; ++nt)
            acc[mt][nt] = __builtin_amdgcn_mfma_f32_16x16x32_bf16(aw[mt], bx[nt], acc[mt][nt], 0, 0, 0);
      }
      const int sb = (pj == 0) ? QS : KS;
#pragma unroll
      for (int mt = 0; mt < 2; ++mt) {
        float4 b4 = *reinterpret_cast<const float4*>(&wB[pj * 128 + c0 + mt * 16 + kg * 4]);
#pragma unroll
        for (int nt = 0; nt < 2; ++nt) {
          int tok = t0 + nt * 16 + lr;
          if (tok < 49) {
            ushort4 h4 = { f2bf(acc[mt][nt][0] + b4.x), f2bf(acc[mt][nt][1] + b4.y),
                           f2bf(acc[mt][nt][2] + b4.z), f2bf(acc[mt][nt][3] + b4.w) };
            *reinterpret_cast<ushort4*>(&L[sb + tok * 136 + c0 + mt * 16 + kg * 4]) = h4;
          }
        }
      }
    }
    {  // v: D[tok][co] -> vT[co][tok]
      const ushort* W = wW + 2 * 16384;
      f32x4 acc[2][2] = {};
#pragma unroll
      for (int kk = 0; kk < 4; ++kk) {
        bf16x8 ax[2], bw[2];
#pragma unroll
        for (int mt = 0; mt < 2; ++mt) {
          int tok = t0 + mt * 16 + lr; if (tok > 48) tok = 48;
          ax[mt] = *reinterpret_cast<const bf16x8*>(&L[tok * 136 + kk * 32 + kg * 8]);
        }
#pragma unroll
        for (int nt = 0; nt < 2; ++nt)
          bw[nt] = *reinterpret_cast<const bf16x8*>(&W[(c0 + nt * 16 + lr) * 128 + kk * 32 + kg * 8]);
#pragma unroll
        for (int mt = 0; mt < 2; ++mt)
#pragma unroll
          for (int nt = 0; nt < 2; ++nt)
            acc[mt][nt] = __builtin_amdgcn_mfma_f32_16x16x32_bf16(ax[mt], bw[nt], acc[mt][nt], 0, 0, 0);
      }
#pragma unroll
      for (int nt = 0; nt < 2; ++nt) {
        float bias = wB[256 + c0 + nt * 16 + lr];
#pragma unroll
        for (int mt = 0; mt < 2; ++mt) {
          ushort4 h4 = { f2bf(acc[mt][nt][0] + bias), f2bf(acc[mt][nt][1] + bias),
                         f2bf(acc[mt][nt][2] + bias), f2bf(acc[mt][nt][3] + bias) };
          *reinterpret_cast<ushort4*>(&L[VT + (c0 + nt * 16 + lr) * 72 + t0 + mt * 16 + kg * 4]) = h4;
        }
      }
    }
  }
  __syncthreads();

  // ---------------- Attention x2 (no barrier between windows; wave-private P rows) ----------------
  f32x4 oacc[2][2][2] = {};  // [w][pass][mt]
#pragma unroll
  for (int w = 0; w < 2; ++w) {
    ushort* L = lds + w * 31760;
    const int cls = clsA[w];
#pragma unroll
    for (int pass = 0; pass < 2; ++pass) {
      const int h = pass * 2 + hloc;
      f32x4 s[4] = {};
      {
        bf16x8 bq = *reinterpret_cast<const bf16x8*>(&L[QS + qtc * 136 + h * 32 + kg * 8]);
#pragma unroll
        for (int at = 0; at < 4; ++at) {
          int kt = at * 16 + lr; if (kt > 48) kt = 48;
          bf16x8 ak = *reinterpret_cast<const bf16x8*>(&L[KS + kt * 136 + h * 32 + kg * 8]);
          s[at] = __builtin_amdgcn_mfma_f32_16x16x32_bf16(ak, bq, s[at], 0, 0, 0);
        }
      }
      const float* rp = wRM + (((size_t)cls * 4 + h) * 64 + qt) * 64;
      float mx = -3.0e38f;
#pragma unroll
      for (int at = 0; at < 4; ++at) {
        float4 r4 = *reinterpret_cast<const float4*>(&rp[at * 16 + kg * 4]);
        s[at][0] += r4.x; s[at][1] += r4.y; s[at][2] += r4.z; s[at][3] += r4.w;
        mx = fmaxf(mx, fmaxf(fmaxf(s[at][0], s[at][1]), fmaxf(s[at][2], s[at][3])));
      }
      mx = fmaxf(mx, __shfl_xor(mx, 16));
      mx = fmaxf(mx, __shfl_xor(mx, 32));
      float sum = 0.0f;
#pragma unroll
      for (int at = 0; at < 4; ++at) {
#pragma unroll
        for (int i = 0; i < 4; ++i) {
          float e = __expf(s[at][i] - mx);
          s[at][i] = e; sum += e;
        }
      }
      sum += __shfl_xor(sum, 16);
      sum += __shfl_xor(sum, 32);
      float inv = 1.0f / sum;
      const int pb = hloc * 4608 + qt * 72;
#pragma unroll
      for (int at = 0; at < 4; ++at) {
        ushort4 p4 = { f2bf(s[at][0] * inv), f2bf(s[at][1] * inv),
                       f2bf(s[at][2] * inv), f2bf(s[at][3] * inv) };
        *reinterpret_cast<ushort4*>(&L[pb + at * 16 + kg * 4]) = p4;
      }
#pragma unroll
      for (int kk = 0; kk < 2; ++kk) {
        bf16x8 bp = *reinterpret_cast<const bf16x8*>(&L[pb + kk * 32 + kg * 8]);
#pragma unroll
        for (int mt = 0; mt < 2; ++mt) {
          bf16x8 av = *reinterpret_cast<const bf16x8*>(&L[VT + (h * 32 + mt * 16 + lr) * 72 + kk * 32 + kg * 8]);
          oacc[w][pass][mt] = __builtin_amdgcn_mfma_f32_16x16x32_bf16(av, bp, oacc[w][pass][mt], 0, 0, 0);
        }
      }
    }
  }
  __syncthreads();  // all p_s reads done before o_s overwrites

  // ---------------- O -> o_s x2 ----------------
#pragma unroll
  for (int w = 0; w < 2; ++w) {
    ushort* L = lds + w * 31760;
#pragma unroll
    for (int pass = 0; pass < 2; ++pass) {
      const int h = pass * 2 + hloc;
#pragma unroll
      for (int mt = 0; mt < 2; ++mt) {
        if (qt < 49) {
          ushort4 h4 = { f2bf(oacc[w][pass][mt][0]), f2bf(oacc[w][pass][mt][1]),
                         f2bf(oacc[w][pass][mt][2]), f2bf(oacc[w][pass][mt][3]) };
          *reinterpret_cast<ushort4*>(&L[qt * 136 + h * 32 + mt * 16 + kg * 4]) = h4;
        }
      }
    }
  }
  __syncthreads();

  // ---------------- Phase E x2: output projection + float4 scatter ----------------
#pragma unroll
  for (int w = 0; w < 2; ++w) {
    ushort* L = lds + w * 31760;
    const int wi = wiA[w], wj = wjA[w];
    const ushort* W = wW + 3 * 16384;
    f32x4 acc[2][2] = {};
#pragma unroll
    for (int kk = 0; kk < 4; ++kk) {
      bf16x8 aw[2], bo[2];
#pragma unroll
      for (int mt = 0; mt < 2; ++mt)
        aw[mt] = *reinterpret_cast<const bf16x8*>(&W[(c0 + mt * 16 + lr) * 128 + kk * 32 + kg * 8]);
#pragma unroll
      for (int nt = 0; nt < 2; ++nt) {
        int tok = t0 + nt * 16 + lr; if (tok > 48) tok = 48;
        bo[nt] = *reinterpret_cast<const bf16x8*>(&L[tok * 136 + kk * 32 + kg * 8]);
      }
#pragma unroll
      for (int mt = 0; mt < 2; ++mt)
#pragma unroll
        for (int nt = 0; nt < 2; ++nt)
          acc[mt][nt] = __builtin_amdgcn_mfma_f32_16x16x32_bf16(aw[mt], bo[nt], acc[mt][nt], 0, 0, 0);
    }
#pragma unroll
    for (int mt = 0; mt < 2; ++mt) {
      float4 b4 = *reinterpret_cast<const float4*>(&wB[384 + c0 + mt * 16 + kg * 4]);
#pragma unroll
      for (int nt = 0; nt < 2; ++nt) {
        int tok = t0 + nt * 16 + lr;
        if (tok < 49) {
          int r = d7(tok), c = tok - r * 7;
          int gh = wi * 7 + r + SHF; if (gh >= IMG) gh -= IMG;
          int gw = wj * 7 + c + SHF; if (gw >= IMG) gw -= IMG;
          float4 o4 = { acc[mt][nt][0] + b4.x, acc[mt][nt][1] + b4.y,
                        acc[mt][nt][2] + b4.z, acc[mt][nt][3] + b4.w };
          *reinterpret_cast<float4*>(out + gBase + ((size_t)gh * IMG + gw) * 128 + c0 + mt * 16 + kg * 4) = o4;
        }
      }
    }
  }
}

extern "C" void kernel_launch(void* const* d_in, const int* in_sizes, int n_in,
                              void* d_out, int out_size, void* d_ws, size_t ws_size,
                              hipStream_t stream) {
  const float* X = (const float*)d_in[0];
  const float* Wq = (const float*)d_in[3];
  const float* Wk = (const float*)d_in[4];
  const float* Wv = (const float*)d_in[5];
  const float* Wp = (const float*)d_in[6];
  const float* bq = (const float*)d_in[7];
  const float* bk = (const float*)d_in[8];
  const float* bv = (const float*)d_in[9];
  const float* bp = (const float*)d_in[10];
  const float* tbl = (const float*)d_in[11];

  ushort* wW = (ushort*)d_ws;                             // 4 x [128][128] bf16 = 131072 B
  float* wB = (float*)((char*)d_ws + 131072);             // 4 x [128] f32   = 2048 B
  float* wRM = (float*)((char*)d_ws + 131072 + 2048);     // [4][4][64][64] f32 = 262144 B

  prep_kernel<<<dim3(514), dim3(256), 0, stream>>>(Wq, Wk, Wv, Wp, bq, bk, bv, bp, tbl, wW, wB, wRM);
  swin_kernel<<<dim3(4096), dim3(512), 0, stream>>>(X, wW, wB, wRM, (float*)d_out);
}

// Round 10
// 411.504 us; speedup vs baseline: 3.0211x; 1.0024x over previous
//
#include <hip/hip_runtime.h>

typedef __attribute__((ext_vector_type(8))) __bf16 bf16x8;
typedef __attribute__((ext_vector_type(4))) float f32x4;

#define IMG 112
#define SHF 3

__device__ __forceinline__ ushort f2bf(float f) {
  return __builtin_bit_cast(unsigned short, static_cast<__bf16>(f));
}
__device__ __forceinline__ uint pk2(float lo, float hi) {
  return (uint)f2bf(lo) | ((uint)f2bf(hi) << 16);
}
__device__ __forceinline__ int d7(int n) { return (n * 9363) >> 16; }  // n/7 for n<=63

// Zero-padded K=16 embedding into the K=32 bf16 MFMA:
// B-frag regs {pkA, pkB, 0, 0} -> lane kg contributes k' = 8*kg + {0..3} only.
__device__ __forceinline__ bf16x8 padu2(uint a, uint b) {
  union { uint4 u; bf16x8 v; } r;
  r.u = uint4{ a, b, 0u, 0u };
  return r.v;
}
__device__ __forceinline__ bf16x8 padu4(ushort4 x) {
  union { ushort4 s; uint2 u; } a; a.s = x;
  return padu2(a.u.x, a.u.y);
}

// ---------------- prep: bf16 weights (+q scale fold), biases, rpb+mask table ----------------
// wRM[cls][h][64 qt][64 kt]: rpb + (-100 shift mask) + (-1e30 for kt>=49 pad); 0 for qt>=49.
__global__ void prep_kernel(const float* __restrict__ Wq, const float* __restrict__ Wk,
                            const float* __restrict__ Wv, const float* __restrict__ Wp,
                            const float* __restrict__ bq, const float* __restrict__ bk,
                            const float* __restrict__ bv, const float* __restrict__ bp,
                            const float* __restrict__ tbl,
                            ushort* __restrict__ wW, float* __restrict__ wB,
                            float* __restrict__ wRM) {
  int t = blockIdx.x * 256 + threadIdx.x;
  const float SC = 0.17677669529663687f;  // 32^-0.5
  if (t < 65536) {
    int m = t >> 14, e = t & 16383;
    const float* W = (m == 0) ? Wq : (m == 1) ? Wk : (m == 2) ? Wv : Wp;
    float v = W[e];
    if (m == 0) v *= SC;
    wW[t] = f2bf(v);
  } else if (t < 66048) {
    int t2 = t - 65536;
    int m = t2 >> 7, e = t2 & 127;
    const float* B = (m == 0) ? bq : (m == 1) ? bk : (m == 2) ? bv : bp;
    float v = B[e];
    if (m == 0) v *= SC;
    wB[t2] = v;
  } else if (t < 131584) {
    int t3 = t - 66048;  // [0, 65536)
    int cls = t3 >> 14;
    int r = t3 & 16383;
    int h = r >> 12;
    int rr = r & 4095;
    int qt = rr >> 6, kt = rr & 63;
    float v;
    if (qt >= 49) v = 0.0f;
    else if (kt >= 49) v = -1e30f;
    else {
      int rq = qt / 7, cq = qt % 7, rk = kt / 7, ck = kt % 7;
      v = tbl[((rq - rk + 6) * 13 + (cq - ck + 6)) * 4 + h];
      int eH = (cls >> 1) & 1, eW = cls & 1;
      int ridq = (eH ? (rq < 4 ? 3 : 6) : 0) + (eW ? (cq < 4 ? 1 : 2) : 0);
      int ridk = (eH ? (rk < 4 ? 3 : 6) : 0) + (eW ? (ck < 4 ? 1 : 2) : 0);
      if (ridq != ridk) v -= 100.0f;
    }
    wRM[t3] = v;
  }
}

// LDS layout (ushort units), 25096 = 50.2 KB:
//  R0 [0, 9216)      : x_s[49][136]  (aliased as o_s[49][136] after attn; wave-private rows)
//  KS [9216, 15880)  : k_s[49][136]  ([token][channel])
//  VT [15880, 25096) : vT[128][72]   ([channel][token])
#define KS 9216
#define VT 15880

__global__ __launch_bounds__(512, 4) void swin_kernel(
    const float* __restrict__ X, const ushort* __restrict__ wW,
    const float* __restrict__ wB, const float* __restrict__ wRM,
    float* __restrict__ out) {
  __shared__ ushort lds[25096];
  const int tid = threadIdx.x;
  const int wv = tid >> 6;  // 0..7
  const int lane = tid & 63;
  const int lr = lane & 15;
  const int kg = lane >> 4;

  const int blk = blockIdx.x;
  const int b = blk >> 8;
  const int wid = blk & 255;
  const int wi = wid >> 4, wj = wid & 15;
  const size_t gBase = (size_t)b * (IMG * IMG * 128);

  // ---------------- Phase A: gather rolled window, f32 -> bf16 ----------------
#pragma unroll 1
  for (int idx = tid; idx < 49 * 32; idx += 512) {
    int row = idx >> 5, q4 = idx & 31;
    int r = d7(row), c = row - r * 7;
    int gh = wi * 7 + r + SHF; if (gh >= IMG) gh -= IMG;
    int gw = wj * 7 + c + SHF; if (gw >= IMG) gw -= IMG;
    float4 v = reinterpret_cast<const float4*>(X + gBase + ((size_t)gh * IMG + gw) * 128)[q4];
    ushort4 h4 = { f2bf(v.x), f2bf(v.y), f2bf(v.z), f2bf(v.w) };
    *reinterpret_cast<ushort4*>(&lds[row * 136 + q4 * 4]) = h4;
  }
  __syncthreads();

  const int wc = wv & 3, wt = wv >> 2;
  const int c0 = wc * 32, t0 = wt * 32;
  const int hloc = wv >> 2, mq = wv & 3;  // attn identity
  const int qt = mq * 16 + lr;
  const int qtc = qt > 48 ? 48 : qt;

  // ---------------- Phase B0: this wave's Q -> register D-frags (no LDS round trip) ----------------
  // dq[pass][c16]: D[ch][qt] for head pass*2+hloc, ch-slice c16*16, this wave's qt-tile.
  f32x4 dq[2][2] = {};
#pragma unroll
  for (int kk = 0; kk < 4; ++kk) {
    bf16x8 bxq = *reinterpret_cast<const bf16x8*>(&lds[qtc * 136 + kk * 32 + kg * 8]);
#pragma unroll
    for (int pass = 0; pass < 2; ++pass) {
      const int h = pass * 2 + hloc;
#pragma unroll
      for (int c16 = 0; c16 < 2; ++c16) {
        bf16x8 aw = *reinterpret_cast<const bf16x8*>(&wW[(h * 32 + c16 * 16 + lr) * 128 + kk * 32 + kg * 8]);
        dq[pass][c16] = __builtin_amdgcn_mfma_f32_16x16x32_bf16(aw, bxq, dq[pass][c16], 0, 0, 0);
      }
    }
  }
  // bias (rows ch = kg*4+i) then pack to zero-padded B-frags
  bf16x8 qp[2][2];
#pragma unroll
  for (int pass = 0; pass < 2; ++pass) {
    const int h = pass * 2 + hloc;
#pragma unroll
    for (int c16 = 0; c16 < 2; ++c16) {
      float4 b4 = *reinterpret_cast<const float4*>(&wB[h * 32 + c16 * 16 + kg * 4]);
      qp[pass][c16] = padu2(pk2(dq[pass][c16][0] + b4.x, dq[pass][c16][1] + b4.y),
                            pk2(dq[pass][c16][2] + b4.z, dq[pass][c16][3] + b4.w));
    }
  }

  // ---------------- Phase B1: K projection -> k_s[tok][ch] ----------------
  {
    const ushort* W = wW + 16384;
    f32x4 acc[2][2] = {};
#pragma unroll
    for (int kk = 0; kk < 4; ++kk) {
      bf16x8 aw[2], bx[2];
#pragma unroll
      for (int mt = 0; mt < 2; ++mt)
        aw[mt] = *reinterpret_cast<const bf16x8*>(&W[(c0 + mt * 16 + lr) * 128 + kk * 32 + kg * 8]);
#pragma unroll
      for (int nt = 0; nt < 2; ++nt) {
        int tok = t0 + nt * 16 + lr; if (tok > 48) tok = 48;
        bx[nt] = *reinterpret_cast<const bf16x8*>(&lds[tok * 136 + kk * 32 + kg * 8]);
      }
#pragma unroll
      for (int mt = 0; mt < 2; ++mt)
#pragma unroll
        for (int nt = 0; nt < 2; ++nt)
          acc[mt][nt] = __builtin_amdgcn_mfma_f32_16x16x32_bf16(aw[mt], bx[nt], acc[mt][nt], 0, 0, 0);
    }
#pragma unroll
    for (int mt = 0; mt < 2; ++mt) {
      float4 b4 = *reinterpret_cast<const float4*>(&wB[128 + c0 + mt * 16 + kg * 4]);
#pragma unroll
      for (int nt = 0; nt < 2; ++nt) {
        int tok = t0 + nt * 16 + lr;
        if (tok < 49) {
          ushort4 h4 = { f2bf(acc[mt][nt][0] + b4.x), f2bf(acc[mt][nt][1] + b4.y),
                         f2bf(acc[mt][nt][2] + b4.z), f2bf(acc[mt][nt][3] + b4.w) };
          *reinterpret_cast<ushort4*>(&lds[KS + tok * 136 + c0 + mt * 16 + kg * 4]) = h4;
        }
      }
    }
  }
  // ---------------- Phase B2: V projection -> vT[ch][tok] ----------------
  {
    const ushort* W = wW + 2 * 16384;
    f32x4 acc[2][2] = {};
#pragma unroll
    for (int kk = 0; kk < 4; ++kk) {
      bf16x8 ax[2], bw[2];
#pragma unroll
      for (int mt = 0; mt < 2; ++mt) {
        int tok = t0 + mt * 16 + lr; if (tok > 48) tok = 48;
        ax[mt] = *reinterpret_cast<const bf16x8*>(&lds[tok * 136 + kk * 32 + kg * 8]);
      }
#pragma unroll
      for (int nt = 0; nt < 2; ++nt)
        bw[nt] = *reinterpret_cast<const bf16x8*>(&W[(c0 + nt * 16 + lr) * 128 + kk * 32 + kg * 8]);
#pragma unroll
      for (int mt = 0; mt < 2; ++mt)
#pragma unroll
        for (int nt = 0; nt < 2; ++nt)
          acc[mt][nt] = __builtin_amdgcn_mfma_f32_16x16x32_bf16(ax[mt], bw[nt], acc[mt][nt], 0, 0, 0);
    }
#pragma unroll
    for (int nt = 0; nt < 2; ++nt) {
      float bias = wB[256 + c0 + nt * 16 + lr];
#pragma unroll
      for (int mt = 0; mt < 2; ++mt) {
        ushort4 h4 = { f2bf(acc[mt][nt][0] + bias), f2bf(acc[mt][nt][1] + bias),
                       f2bf(acc[mt][nt][2] + bias), f2bf(acc[mt][nt][3] + bias) };
        *reinterpret_cast<ushort4*>(&lds[VT + (c0 + nt * 16 + lr) * 72 + t0 + mt * 16 + kg * 4]) = h4;
      }
    }
  }
  __syncthreads();  // barrier 2: k_s / vT visible

  // ---------------- Attention: zero-repack via K=16 embedding; P in regs ----------------
  const int cls = ((wi == 15) ? 2 : 0) + ((wj == 15) ? 1 : 0);
  f32x4 o[2][2] = {};  // [pass][dt]
  float invs[2];
#pragma unroll
  for (int pass = 0; pass < 2; ++pass) {
    const int h = pass * 2 + hloc;
    // S^T[kt][qt]: contraction over ch in two K=16 steps (c16 = 0,1)
    f32x4 s[4] = {};
#pragma unroll
    for (int at = 0; at < 4; ++at) {
      int kt = at * 16 + lr; if (kt > 48) kt = 48;
#pragma unroll
      for (int c16 = 0; c16 < 2; ++c16) {
        bf16x8 ak = padu4(*reinterpret_cast<const ushort4*>(&lds[KS + kt * 136 + h * 32 + c16 * 16 + kg * 4]));
        s[at] = __builtin_amdgcn_mfma_f32_16x16x32_bf16(ak, qp[pass][c16], s[at], 0, 0, 0);
      }
    }
    // rpb + mask + exp (no max-subtract; clamp); raw P stays in regs
    const float* rp = wRM + (((size_t)cls * 4 + h) * 64 + qt) * 64;
    float sum = 0.0f;
#pragma unroll
    for (int at = 0; at < 4; ++at) {
      float4 r4 = *reinterpret_cast<const float4*>(&rp[at * 16 + kg * 4]);
#pragma unroll
      for (int i = 0; i < 4; ++i) {
        float e = __expf(fminf(s[at][i] + r4[i], 60.0f));
        s[at][i] = e; sum += e;
      }
    }
    // P D-frags -> zero-padded B-frags (in regs, no LDS)
    bf16x8 pf[4];
#pragma unroll
    for (int at = 0; at < 4; ++at)
      pf[at] = padu2(pk2(s[at][0], s[at][1]), pk2(s[at][2], s[at][3]));
    // O^T[d][qt] += V^T P^T, K=16 steps over kt
#pragma unroll
    for (int dt = 0; dt < 2; ++dt) {
      const int d = h * 32 + dt * 16 + lr;
#pragma unroll
      for (int at = 0; at < 4; ++at) {
        bf16x8 av = padu4(*reinterpret_cast<const ushort4*>(&lds[VT + d * 72 + at * 16 + kg * 4]));
        o[pass][dt] = __builtin_amdgcn_mfma_f32_16x16x32_bf16(av, pf[at], o[pass][dt], 0, 0, 0);
      }
    }
    // deferred row-sum (off the MFMA chain)
    sum += __shfl_xor(sum, 16);
    sum += __shfl_xor(sum, 32);
    invs[pass] = 1.0f / sum;
  }

  // ---------------- O (scaled) -> o_s[tok][ch] (aliases x_s; x_s no longer read) ----------------
  if (qt < 49) {
#pragma unroll
    for (int pass = 0; pass < 2; ++pass) {
      const int h = pass * 2 + hloc;
      float inv = invs[pass];
#pragma unroll
      for (int dt = 0; dt < 2; ++dt) {
        ushort4 h4 = { f2bf(o[pass][dt][0] * inv), f2bf(o[pass][dt][1] * inv),
                       f2bf(o[pass][dt][2] * inv), f2bf(o[pass][dt][3] * inv) };
        *reinterpret_cast<ushort4*>(&lds[qt * 136 + h * 32 + dt * 16 + kg * 4]) = h4;
      }
    }
  }
  __syncthreads();  // barrier 3: o_s complete

  // ---------------- Phase E: output projection (swapped) + float4 scatter ----------------
  {
    const ushort* W = wW + 3 * 16384;
    f32x4 acc[2][2] = {};
#pragma unroll
    for (int kk = 0; kk < 4; ++kk) {
      bf16x8 aw[2], bo[2];
#pragma unroll
      for (int mt = 0; mt < 2; ++mt)
        aw[mt] = *reinterpret_cast<const bf16x8*>(&W[(c0 + mt * 16 + lr) * 128 + kk * 32 + kg * 8]);
#pragma unroll
      for (int nt = 0; nt < 2; ++nt) {
        int tok = t0 + nt * 16 + lr; if (tok > 48) tok = 48;
        bo[nt] = *reinterpret_cast<const bf16x8*>(&lds[tok * 136 + kk * 32 + kg * 8]);
      }
#pragma unroll
      for (int mt = 0; mt < 2; ++mt)
#pragma unroll
        for (int nt = 0; nt < 2; ++nt)
          acc[mt][nt] = __builtin_amdgcn_mfma_f32_16x16x32_bf16(aw[mt], bo[nt], acc[mt][nt], 0, 0, 0);
    }
#pragma unroll
    for (int mt = 0; mt < 2; ++mt) {
      float4 b4 = *reinterpret_cast<const float4*>(&wB[384 + c0 + mt * 16 + kg * 4]);
#pragma unroll
      for (int nt = 0; nt < 2; ++nt) {
        int tok = t0 + nt * 16 + lr;
        if (tok < 49) {
          int r = d7(tok), c = tok - r * 7;
          int gh = wi * 7 + r + SHF; if (gh >= IMG) gh -= IMG;
          int gw = wj * 7 + c + SHF; if (gw >= IMG) gw -= IMG;
          float4 o4 = { acc[mt][nt][0] + b4.x, acc[mt][nt][1] + b4.y,
                        acc[mt][nt][2] + b4.z, acc[mt][nt][3] + b4.w };
          *reinterpret_cast<float4*>(out + gBase + ((size_t)gh * IMG + gw) * 128 + c0 + mt * 16 + kg * 4) = o4;
        }
      }
    }
  }
}

extern "C" void kernel_launch(void* const* d_in, const int* in_sizes, int n_in,
                              void* d_out, int out_size, void* d_ws, size_t ws_size,
                              hipStream_t stream) {
  const float* X = (const float*)d_in[0];
  const float* Wq = (const float*)d_in[3];
  const float* Wk = (const float*)d_in[4];
  const float* Wv = (const float*)d_in[5];
  const float* Wp = (const float*)d_in[6];
  const float* bq = (const float*)d_in[7];
  const float* bk = (const float*)d_in[8];
  const float* bv = (const float*)d_in[9];
  const float* bp = (const float*)d_in[10];
  const float* tbl = (const float*)d_in[11];

  ushort* wW = (ushort*)d_ws;                             // 4 x [128][128] bf16 = 131072 B
  float* wB = (float*)((char*)d_ws + 131072);             // 4 x [128] f32   = 2048 B
  float* wRM = (float*)((char*)d_ws + 131072 + 2048);     // [4][4][64][64] f32 = 262144 B

  prep_kernel<<<dim3(514), dim3(256), 0, stream>>>(Wq, Wk, Wv, Wp, bq, bk, bv, bp, tbl, wW, wB, wRM);
  swin_kernel<<<dim3(8192), dim3(512), 0, stream>>>(X, wW, wB, wRM, (float*)d_out);
}

// Round 11
// 344.298 us; speedup vs baseline: 3.6108x; 1.1952x over previous
//
#include <hip/hip_runtime.h>

typedef __attribute__((ext_vector_type(8))) __bf16 bf16x8;
typedef __attribute__((ext_vector_type(4))) float f32x4;

#define IMG 112
#define SHF 3

__device__ __forceinline__ ushort f2bf(float f) {
  return __builtin_bit_cast(unsigned short, static_cast<__bf16>(f));
}
__device__ __forceinline__ int d7(int n) { return (n * 9363) >> 16; }  // n/7 for n<=63

// ---------------- prep: bf16 weights (+q scale fold), biases, rpb+mask table ----------------
// wRM[cls][h][64 qt][64 kt]: rpb + (-100 shift mask) + (-1e30 for kt>=49 pad); 0 for qt>=49.
__global__ void prep_kernel(const float* __restrict__ Wq, const float* __restrict__ Wk,
                            const float* __restrict__ Wv, const float* __restrict__ Wp,
                            const float* __restrict__ bq, const float* __restrict__ bk,
                            const float* __restrict__ bv, const float* __restrict__ bp,
                            const float* __restrict__ tbl,
                            ushort* __restrict__ wW, float* __restrict__ wB,
                            float* __restrict__ wRM) {
  int t = blockIdx.x * 256 + threadIdx.x;
  const float SC = 0.17677669529663687f;  // 32^-0.5
  if (t < 65536) {
    int m = t >> 14, e = t & 16383;
    const float* W = (m == 0) ? Wq : (m == 1) ? Wk : (m == 2) ? Wv : Wp;
    float v = W[e];
    if (m == 0) v *= SC;
    wW[t] = f2bf(v);
  } else if (t < 66048) {
    int t2 = t - 65536;
    int m = t2 >> 7, e = t2 & 127;
    const float* B = (m == 0) ? bq : (m == 1) ? bk : (m == 2) ? bv : bp;
    float v = B[e];
    if (m == 0) v *= SC;
    wB[t2] = v;
  } else if (t < 131584) {
    int t3 = t - 66048;  // [0, 65536)
    int cls = t3 >> 14;
    int r = t3 & 16383;
    int h = r >> 12;
    int rr = r & 4095;
    int qt = rr >> 6, kt = rr & 63;
    float v;
    if (qt >= 49) v = 0.0f;
    else if (kt >= 49) v = -1e30f;
    else {
      int rq = qt / 7, cq = qt % 7, rk = kt / 7, ck = kt % 7;
      v = tbl[((rq - rk + 6) * 13 + (cq - ck + 6)) * 4 + h];
      int eH = (cls >> 1) & 1, eW = cls & 1;
      int ridq = (eH ? (rq < 4 ? 3 : 6) : 0) + (eW ? (cq < 4 ? 1 : 2) : 0);
      int ridk = (eH ? (rk < 4 ? 3 : 6) : 0) + (eW ? (ck < 4 ? 1 : 2) : 0);
      if (ridq != ridk) v -= 100.0f;
    }
    wRM[t3] = v;
  }
}

// LDS layout (ushort units):
//  [0, 9216)      : x_s[49][136] (A/B)  |  p_s[2][64][72] (attn)
//  [9216, 15880)  : q_s[49][136]  (aliased as o_s after attn; wave-private rows)
//  [15880, 22544) : k_s[49][136]
//  [22544, 31760) : vT[128][72]   (v transposed: [channel][token])
#define QS 9216
#define KS 15880
#define VT 22544

__global__ __launch_bounds__(512, 4) void swin_kernel(
    const float* __restrict__ X, const ushort* __restrict__ wW,
    const float* __restrict__ wB, const float* __restrict__ wRM,
    float* __restrict__ out) {
  __shared__ ushort lds[31760];
  const int tid = threadIdx.x;
  const int wv = tid >> 6;  // 0..7
  const int lane = tid & 63;
  const int lr = lane & 15;
  const int kg = lane >> 4;

  const int blk = blockIdx.x;
  const int b = blk >> 8;
  const int wid = blk & 255;
  const int wi = wid >> 4, wj = wid & 15;
  const size_t gBase = (size_t)b * (IMG * IMG * 128);

  // ---------------- Phase A: 4 independent load->store chains (all loads in flight) ----------------
  {
    float4 va[4]; int rowa[4], q4a[4]; bool ok[4];
#pragma unroll
    for (int i = 0; i < 4; ++i) {
      int idx = tid + i * 512;
      ok[i] = idx < 49 * 32;
      int row = idx >> 5, q4 = idx & 31;
      rowa[i] = row; q4a[i] = q4;
      if (ok[i]) {
        int r = d7(row), c = row - r * 7;
        int gh = wi * 7 + r + SHF; if (gh >= IMG) gh -= IMG;
        int gw = wj * 7 + c + SHF; if (gw >= IMG) gw -= IMG;
        va[i] = reinterpret_cast<const float4*>(X + gBase + ((size_t)gh * IMG + gw) * 128)[q4];
      }
    }
#pragma unroll
    for (int i = 0; i < 4; ++i) {
      if (ok[i]) {
        ushort4 h4 = { f2bf(va[i].x), f2bf(va[i].y), f2bf(va[i].z), f2bf(va[i].w) };
        *reinterpret_cast<ushort4*>(&lds[rowa[i] * 136 + q4a[i] * 4]) = h4;
      }
    }
  }
  __syncthreads();

  const int wc = wv & 3, wt = wv >> 2;
  const int c0 = wc * 32, t0 = wt * 32;
  const int hloc = wv >> 2, mq = wv & 3;  // attn identity
  const int qt = mq * 16 + lr;
  const int qtc = qt > 48 ? 48 : qt;

  // ---------------- Phase B: QKV projections, fully hoisted loads ----------------
#pragma unroll
  for (int pj = 0; pj < 2; ++pj) {  // q, k: D[co][tok]
    const ushort* W = wW + pj * 16384;
    bf16x8 aw[4][2], bx[4][2];
#pragma unroll
    for (int kk = 0; kk < 4; ++kk)    // global (L2) first
#pragma unroll
      for (int mt = 0; mt < 2; ++mt)
        aw[kk][mt] = *reinterpret_cast<const bf16x8*>(&W[(c0 + mt * 16 + lr) * 128 + kk * 32 + kg * 8]);
#pragma unroll
    for (int kk = 0; kk < 4; ++kk)    // LDS second
#pragma unroll
      for (int nt = 0; nt < 2; ++nt) {
        int tok = t0 + nt * 16 + lr; if (tok > 48) tok = 48;
        bx[kk][nt] = *reinterpret_cast<const bf16x8*>(&lds[tok * 136 + kk * 32 + kg * 8]);
      }
    f32x4 acc[2][2] = {};
#pragma unroll
    for (int kk = 0; kk < 4; ++kk)
#pragma unroll
      for (int mt = 0; mt < 2; ++mt)
#pragma unroll
        for (int nt = 0; nt < 2; ++nt)
          acc[mt][nt] = __builtin_amdgcn_mfma_f32_16x16x32_bf16(aw[kk][mt], bx[kk][nt], acc[mt][nt], 0, 0, 0);
    const int sb = (pj == 0) ? QS : KS;
#pragma unroll
    for (int mt = 0; mt < 2; ++mt) {
      float4 b4 = *reinterpret_cast<const float4*>(&wB[pj * 128 + c0 + mt * 16 + kg * 4]);
#pragma unroll
      for (int nt = 0; nt < 2; ++nt) {
        int tok = t0 + nt * 16 + lr;
        if (tok < 49) {
          ushort4 h4 = { f2bf(acc[mt][nt][0] + b4.x), f2bf(acc[mt][nt][1] + b4.y),
                         f2bf(acc[mt][nt][2] + b4.z), f2bf(acc[mt][nt][3] + b4.w) };
          *reinterpret_cast<ushort4*>(&lds[sb + tok * 136 + c0 + mt * 16 + kg * 4]) = h4;
        }
      }
    }
  }
  {  // v: D[tok][co] -> vT[co][tok]
    const ushort* W = wW + 2 * 16384;
    bf16x8 bw[4][2], ax[4][2];
#pragma unroll
    for (int kk = 0; kk < 4; ++kk)
#pragma unroll
      for (int nt = 0; nt < 2; ++nt)
        bw[kk][nt] = *reinterpret_cast<const bf16x8*>(&W[(c0 + nt * 16 + lr) * 128 + kk * 32 + kg * 8]);
#pragma unroll
    for (int kk = 0; kk < 4; ++kk)
#pragma unroll
      for (int mt = 0; mt < 2; ++mt) {
        int tok = t0 + mt * 16 + lr; if (tok > 48) tok = 48;
        ax[kk][mt] = *reinterpret_cast<const bf16x8*>(&lds[tok * 136 + kk * 32 + kg * 8]);
      }
    f32x4 acc[2][2] = {};
#pragma unroll
    for (int kk = 0; kk < 4; ++kk)
#pragma unroll
      for (int mt = 0; mt < 2; ++mt)
#pragma unroll
        for (int nt = 0; nt < 2; ++nt)
          acc[mt][nt] = __builtin_amdgcn_mfma_f32_16x16x32_bf16(ax[kk][mt], bw[kk][nt], acc[mt][nt], 0, 0, 0);
#pragma unroll
    for (int nt = 0; nt < 2; ++nt) {
      float bias = wB[256 + c0 + nt * 16 + lr];
#pragma unroll
      for (int mt = 0; mt < 2; ++mt) {
        ushort4 h4 = { f2bf(acc[mt][nt][0] + bias), f2bf(acc[mt][nt][1] + bias),
                       f2bf(acc[mt][nt][2] + bias), f2bf(acc[mt][nt][3] + bias) };
        *reinterpret_cast<ushort4*>(&lds[VT + (c0 + nt * 16 + lr) * 72 + t0 + mt * 16 + kg * 4]) = h4;
      }
    }
  }
  __syncthreads();

  // ---------------- Attention: swapped QK^T; per-pass loads batched up front ----------------
  const int cls = ((wi == 15) ? 2 : 0) + ((wj == 15) ? 1 : 0);
  f32x4 oacc[2][2] = {};
#pragma unroll
  for (int pass = 0; pass < 2; ++pass) {
    const int h = pass * 2 + hloc;
    // rpb (L2, longest latency) first
    const float* rp = wRM + (((size_t)cls * 4 + h) * 64 + qt) * 64;
    float4 r4[4];
#pragma unroll
    for (int at = 0; at < 4; ++at)
      r4[at] = *reinterpret_cast<const float4*>(&rp[at * 16 + kg * 4]);
    // all LDS reads of this pass batched: Q, K, and V (V independent of softmax)
    bf16x8 bq = *reinterpret_cast<const bf16x8*>(&lds[QS + qtc * 136 + h * 32 + kg * 8]);
    bf16x8 ak[4];
#pragma unroll
    for (int at = 0; at < 4; ++at) {
      int kt = at * 16 + lr; if (kt > 48) kt = 48;
      ak[at] = *reinterpret_cast<const bf16x8*>(&lds[KS + kt * 136 + h * 32 + kg * 8]);
    }
    bf16x8 av[2][2];
#pragma unroll
    for (int kk = 0; kk < 2; ++kk)
#pragma unroll
      for (int mt = 0; mt < 2; ++mt)
        av[kk][mt] = *reinterpret_cast<const bf16x8*>(&lds[VT + (h * 32 + mt * 16 + lr) * 72 + kk * 32 + kg * 8]);
    // S^T = K Q^T
    f32x4 s[4] = {};
#pragma unroll
    for (int at = 0; at < 4; ++at)
      s[at] = __builtin_amdgcn_mfma_f32_16x16x32_bf16(ak[at], bq, s[at], 0, 0, 0);
    // softmax over kt (16 in-lane + 2 shfl)
    float mx = -3.0e38f;
#pragma unroll
    for (int at = 0; at < 4; ++at) {
      s[at][0] += r4[at].x; s[at][1] += r4[at].y; s[at][2] += r4[at].z; s[at][3] += r4[at].w;
      mx = fmaxf(mx, fmaxf(fmaxf(s[at][0], s[at][1]), fmaxf(s[at][2], s[at][3])));
    }
    mx = fmaxf(mx, __shfl_xor(mx, 16));
    mx = fmaxf(mx, __shfl_xor(mx, 32));
    float sum = 0.0f;
#pragma unroll
    for (int at = 0; at < 4; ++at) {
#pragma unroll
      for (int i = 0; i < 4; ++i) {
        float e = __expf(s[at][i] - mx);
        s[at][i] = e; sum += e;
      }
    }
    sum += __shfl_xor(sum, 16);
    sum += __shfl_xor(sum, 32);
    float inv = 1.0f / sum;
    const int pb = hloc * 4608 + qt * 72;
#pragma unroll
    for (int at = 0; at < 4; ++at) {
      ushort4 p4 = { f2bf(s[at][0] * inv), f2bf(s[at][1] * inv),
                     f2bf(s[at][2] * inv), f2bf(s[at][3] * inv) };
      *reinterpret_cast<ushort4*>(&lds[pb + at * 16 + kg * 4]) = p4;
    }
    // O^T = V^T P^T (V already in regs; only bp reads remain on the chain)
#pragma unroll
    for (int kk = 0; kk < 2; ++kk) {
      bf16x8 bp = *reinterpret_cast<const bf16x8*>(&lds[pb + kk * 32 + kg * 8]);
#pragma unroll
      for (int mt = 0; mt < 2; ++mt)
        oacc[pass][mt] = __builtin_amdgcn_mfma_f32_16x16x32_bf16(av[kk][mt], bp, oacc[pass][mt], 0, 0, 0);
    }
  }

  // ---------------- O -> o_s (aliased on q_s; wave-private row qt, no barrier) ----------------
#pragma unroll
  for (int pass = 0; pass < 2; ++pass) {
#pragma unroll
    for (int mt = 0; mt < 2; ++mt) {
      if (qt < 49) {
        ushort4 h4 = { f2bf(oacc[pass][mt][0]), f2bf(oacc[pass][mt][1]),
                       f2bf(oacc[pass][mt][2]), f2bf(oacc[pass][mt][3]) };
        *reinterpret_cast<ushort4*>(&lds[QS + qt * 136 + (pass * 2 + hloc) * 32 + mt * 16 + kg * 4]) = h4;
      }
    }
  }
  // ---------------- Phase E weights issued BEFORE the barrier (global, independent of o_s) ----
  bf16x8 eaw[4][2];
  {
    const ushort* W = wW + 3 * 16384;
#pragma unroll
    for (int kk = 0; kk < 4; ++kk)
#pragma unroll
      for (int mt = 0; mt < 2; ++mt)
        eaw[kk][mt] = *reinterpret_cast<const bf16x8*>(&W[(c0 + mt * 16 + lr) * 128 + kk * 32 + kg * 8]);
  }
  __syncthreads();

  // ---------------- Phase E: output projection (swapped) + float4 scatter ----------------
  {
    bf16x8 bo[4][2];
#pragma unroll
    for (int kk = 0; kk < 4; ++kk)
#pragma unroll
      for (int nt = 0; nt < 2; ++nt) {
        int tok = t0 + nt * 16 + lr; if (tok > 48) tok = 48;
        bo[kk][nt] = *reinterpret_cast<const bf16x8*>(&lds[QS + tok * 136 + kk * 32 + kg * 8]);
      }
    f32x4 acc[2][2] = {};
#pragma unroll
    for (int kk = 0; kk < 4; ++kk)
#pragma unroll
      for (int mt = 0; mt < 2; ++mt)
#pragma unroll
        for (int nt = 0; nt < 2; ++nt)
          acc[mt][nt] = __builtin_amdgcn_mfma_f32_16x16x32_bf16(eaw[kk][mt], bo[kk][nt], acc[mt][nt], 0, 0, 0);
#pragma unroll
    for (int mt = 0; mt < 2; ++mt) {
      float4 b4 = *reinterpret_cast<const float4*>(&wB[384 + c0 + mt * 16 + kg * 4]);
#pragma unroll
      for (int nt = 0; nt < 2; ++nt) {
        int tok = t0 + nt * 16 + lr;
        if (tok < 49) {
          int r = d7(tok), c = tok - r * 7;
          int gh = wi * 7 + r + SHF; if (gh >= IMG) gh -= IMG;
          int gw = wj * 7 + c + SHF; if (gw >= IMG) gw -= IMG;
          float4 o4 = { acc[mt][nt][0] + b4.x, acc[mt][nt][1] + b4.y,
                        acc[mt][nt][2] + b4.z, acc[mt][nt][3] + b4.w };
          *reinterpret_cast<float4*>(out + gBase + ((size_t)gh * IMG + gw) * 128 + c0 + mt * 16 + kg * 4) = o4;
        }
      }
    }
  }
}

extern "C" void kernel_launch(void* const* d_in, const int* in_sizes, int n_in,
                              void* d_out, int out_size, void* d_ws, size_t ws_size,
                              hipStream_t stream) {
  const float* X = (const float*)d_in[0];
  const float* Wq = (const float*)d_in[3];
  const float* Wk = (const float*)d_in[4];
  const float* Wv = (const float*)d_in[5];
  const float* Wp = (const float*)d_in[6];
  const float* bq = (const float*)d_in[7];
  const float* bk = (const float*)d_in[8];
  const float* bv = (const float*)d_in[9];
  const float* bp = (const float*)d_in[10];
  const float* tbl = (const float*)d_in[11];

  ushort* wW = (ushort*)d_ws;                             // 4 x [128][128] bf16 = 131072 B
  float* wB = (float*)((char*)d_ws + 131072);             // 4 x [128] f32   = 2048 B
  float* wRM = (float*)((char*)d_ws + 131072 + 2048);     // [4][4][64][64] f32 = 262144 B

  prep_kernel<<<dim3(514), dim3(256), 0, stream>>>(Wq, Wk, Wv, Wp, bq, bk, bv, bp, tbl, wW, wB, wRM);
  swin_kernel<<<dim3(8192), dim3(512), 0, stream>>>(X, wW, wB, wRM, (float*)d_out);
}